// Round 1
// baseline (192.506 us; speedup 1.0000x reference)
//
#include <hip/hip_runtime.h>

// ---------------------------------------------------------------------------
// MultiHeadAttention with relational-adjacency mask, MI355X (gfx950)
// B=32, L=512, DIM=256, NH=4, HD=64.  SCALE = 8.
//
// Pipeline:
//  cvt_bf16        : x, w_qkv -> bf16
//  cvt_wproj_aug   : w_proj -> [hi|hi|lo] bf16 (for split-precision out proj)
//  bitpack_rows    : adj -> row bitsets (a), + maskA[0] = a|eye
//  transpose_bits  : row bitsets -> col bitsets (aT), + maskA[1] = aT|eye
//  mask23          : maskA[2] = (aT@a != 0)|eye, maskA[3] = (a@aT != 0)|eye
//  gemm_bt<0>      : qkv = x @ w_qkv^T  (bf16 MFMA), scatter to q/k/vT layouts
//  attn            : flash-style masked attention, ctx -> [hi|lo|hi] bf16
//  gemm_bt<1>      : out = ctx_aug @ wproj_aug^T (split bf16 ~ f32 accuracy)
// ---------------------------------------------------------------------------

typedef unsigned long long u64;
typedef unsigned short u16;
typedef short bf16x8 __attribute__((ext_vector_type(8)));
typedef float f32x4 __attribute__((ext_vector_type(4)));

#define MFMA16(a, b, c) __builtin_amdgcn_mfma_f32_16x16x32_bf16((a), (b), (c), 0, 0, 0)

__device__ __forceinline__ unsigned f2bf(float f) {           // f32 -> bf16 (RNE)
  unsigned u = __float_as_uint(f);
  return (u + 0x7FFFu + ((u >> 16) & 1u)) >> 16;
}
__device__ __forceinline__ float bf2f(unsigned b) { return __uint_as_float(b << 16); }

// ---- workspace layout (bytes) ---------------------------------------------
#define OFF_XB    ((size_t)0)          // x bf16        [16384][256]   8,388,608
#define OFF_WQKV  ((size_t)8388608)    // w_qkv bf16    [768][256]       393,216
#define OFF_WPA   ((size_t)8781824)    // w_proj aug    [256][768]       393,216
#define OFF_QB    ((size_t)9175040)    // q bf16        [32][4][512][64] 8,388,608
#define OFF_KB    ((size_t)17563648)   // k bf16        [32][4][512][64] 8,388,608
#define OFF_VTB   ((size_t)25952256)   // vT bf16       [32][4][64][512] 8,388,608
#define OFF_CTXA  ((size_t)34340864)   // ctx aug bf16  [16384][768]    25,165,824
#define OFF_ROWR  ((size_t)59506688)   // row bitsets   [32][512][8]u64  1,048,576
#define OFF_COLR  ((size_t)60555264)   // col bitsets                    1,048,576
#define OFF_MASK  ((size_t)61603840)   // maskA[4][32][512][8]u64        4,194,304
// total 65,798,144 B (~62.8 MB)

// ---------------------------------------------------------------------------
// f32 -> bf16 conversion, 8 elems/thread (n must be multiple of 2048)
__global__ void cvt_bf16(const float* __restrict__ src, u16* __restrict__ dst) {
  size_t i = ((size_t)blockIdx.x * 256 + threadIdx.x) * 8;
  float4 a = *(const float4*)(src + i);
  float4 c = *(const float4*)(src + i + 4);
  uint4 o;
  o.x = f2bf(a.x) | (f2bf(a.y) << 16);
  o.y = f2bf(a.z) | (f2bf(a.w) << 16);
  o.z = f2bf(c.x) | (f2bf(c.y) << 16);
  o.w = f2bf(c.z) | (f2bf(c.w) << 16);
  *(uint4*)(dst + i) = o;
}

// w_proj [256][256] -> augmented [256][768] = [hi | hi | lo]
__global__ void cvt_wproj_aug(const float* __restrict__ wp, u16* __restrict__ wpa) {
  int idx = blockIdx.x * 256 + threadIdx.x;   // 0..65535
  int n = idx >> 8, k = idx & 255;
  float v = wp[idx];
  unsigned hi = f2bf(v);
  unsigned lo = f2bf(v - bf2f(hi));
  size_t base = (size_t)n * 768;
  wpa[base + k]       = (u16)hi;
  wpa[base + 256 + k] = (u16)hi;
  wpa[base + 512 + k] = (u16)lo;
}

// ---------------------------------------------------------------------------
// adj -> row bitsets.  bit = (adj==1 || adj>=9)  (a = binarized adjacency)
// grid (32 b, 8 rc) x 256
__global__ void bitpack_rows(const int* __restrict__ adj, u64* __restrict__ rowraw,
                             u64* __restrict__ maskA0) {
  int b = blockIdx.x, rc = blockIdx.y;
  int wid = threadIdx.x >> 6, lane = threadIdx.x & 63;
  for (int rr = 0; rr < 16; ++rr) {
    int row = rc * 64 + wid * 16 + rr;
    const int* ap = adj + ((size_t)b * 512 + row) * 512;
    for (int wd = 0; wd < 8; ++wd) {
      int v = ap[wd * 64 + lane];
      u64 bal = __ballot(v == 1 || v >= 9);
      if (lane == 0) {
        size_t o = ((size_t)b * 512 + row) * 8 + wd;
        rowraw[o] = bal;
        maskA0[o] = bal | (((row >> 6) == wd) ? (1ull << (row & 63)) : 0ull);
      }
    }
  }
}

// row bitsets -> col bitsets (bit-matrix transpose through LDS). grid 32 x 512
__global__ void transpose_bits(const u64* __restrict__ rowraw, u64* __restrict__ colraw,
                               u64* __restrict__ maskA1) {
  __shared__ u64 bits[4096];   // [512 rows][8 words]
  int b = blockIdx.x, tid = threadIdx.x;
  for (int i = tid; i < 4096; i += 512) bits[i] = rowraw[(size_t)b * 4096 + i];
  __syncthreads();
  int wsel = tid >> 6, bitsel = tid & 63;   // word/bit of column j=tid within a row
  for (int wd = 0; wd < 8; ++wd) {
    u64 word = 0;
    #pragma unroll 1
    for (int t = 0; t < 64; ++t)
      word |= (((bits[(wd * 64 + t) * 8 + wsel] >> bitsel) & 1ull) << t);
    size_t o = ((size_t)b * 512 + tid) * 8 + wd;
    colraw[o] = word;
    maskA1[o] = word | (((tid >> 6) == wd) ? (1ull << (tid & 63)) : 0ull);
  }
}

// m2 = (aT@a != 0)|eye, m3 = (a@aT != 0)|eye.  grid (32 b, 8 qc) x 64
// m3row[q] = OR_{c: a[q][c]} colraw[c];  m2row[q] = OR_{r: a[r][q]} rowraw[r]
__global__ void mask23(const u64* __restrict__ rowraw, const u64* __restrict__ colraw,
                       u64* __restrict__ maskA2, u64* __restrict__ maskA3) {
  __shared__ u64 rb[4096];
  __shared__ u64 cbuf[4096];
  int b = blockIdx.x, qc = blockIdx.y, tid = threadIdx.x;   // 64 threads
  for (int i = tid; i < 4096; i += 64) {
    rb[i]   = rowraw[(size_t)b * 4096 + i];
    cbuf[i] = colraw[(size_t)b * 4096 + i];
  }
  __syncthreads();
  int q = qc * 64 + tid;
  u64 myrow[8], mycol[8];
  #pragma unroll
  for (int w = 0; w < 8; ++w) { myrow[w] = rb[q * 8 + w]; mycol[w] = cbuf[q * 8 + w]; }
  u64 a2[8] = {0, 0, 0, 0, 0, 0, 0, 0}, a3[8] = {0, 0, 0, 0, 0, 0, 0, 0};
  for (int c0 = 0; c0 < 512; c0 += 64) {
    for (int cc = 0; cc < 64; ++cc) {
      int c = c0 + cc;
      u64 p3 = 0ull - ((myrow[c >> 6] >> (c & 63)) & 1ull);
      u64 p2 = 0ull - ((mycol[c >> 6] >> (c & 63)) & 1ull);
      const u64* cr = &cbuf[c * 8];
      const u64* rr = &rb[c * 8];
      #pragma unroll
      for (int w = 0; w < 8; ++w) { a3[w] |= cr[w] & p3; a2[w] |= rr[w] & p2; }
    }
    u64 f = ~0ull;   // early exit: rows saturate to all-ones quickly at 50% density
    #pragma unroll
    for (int w = 0; w < 8; ++w) f &= (a2[w] & a3[w]);
    if (__all((int)(f == ~0ull))) break;
  }
  #pragma unroll
  for (int w = 0; w < 8; ++w) {
    u64 eye = ((q >> 6) == w) ? (1ull << (q & 63)) : 0ull;
    size_t o = ((size_t)b * 512 + q) * 8 + w;
    maskA2[o] = a2[w] | eye;
    maskA3[o] = a3[w] | eye;
  }
}

// ---------------------------------------------------------------------------
// GEMM  C[m][n] = sum_k A[m][k] * Bw[n][k]   (both row-major, K-contiguous)
// 128x128 tile, BK=32, 4 waves (2x2 of 64x64), 16x16x32 bf16 MFMA.
// LDS rows padded to 40 elems (80B = 5x16B -> conflict-free ds_read_b128).
// MODE 0: scatter epilogue -> q[b][h][l][d], k[b][h][l][d], vT[b][h][d][l]
// MODE 1: float epilogue  -> o_f[m][n]  (N=256)
template <int MODE>
__global__ __launch_bounds__(256) void gemm_bt(const u16* __restrict__ A,
                                               const u16* __restrict__ Bw, int Kd,
                                               u16* __restrict__ o_q, u16* __restrict__ o_k,
                                               u16* __restrict__ o_v, float* __restrict__ o_f) {
  __shared__ u16 As[128 * 40];
  __shared__ u16 Bs[128 * 40];
  const int tid = threadIdx.x;
  const int lane = tid & 63, wid = tid >> 6;
  const int lg = lane >> 4, lc = lane & 15;
  const int wm = wid >> 1, wn = wid & 1;
  const int m0 = blockIdx.x * 128, n0 = blockIdx.y * 128;
  f32x4 acc[4][4] = {};
  const int srow = tid >> 1, half = tid & 1;
  const u16* ag = A + (size_t)(m0 + srow) * Kd + half * 16;
  const u16* bg = Bw + (size_t)(n0 + srow) * Kd + half * 16;
  const int lw = srow * 40 + half * 16;

  for (int k0 = 0; k0 < Kd; k0 += 32) {
    uint4 av0 = *(const uint4*)(ag + k0);
    uint4 av1 = *(const uint4*)(ag + k0 + 8);
    uint4 bv0 = *(const uint4*)(bg + k0);
    uint4 bv1 = *(const uint4*)(bg + k0 + 8);
    __syncthreads();
    *(uint4*)&As[lw] = av0; *(uint4*)&As[lw + 8] = av1;
    *(uint4*)&Bs[lw] = bv0; *(uint4*)&Bs[lw + 8] = bv1;
    __syncthreads();
    bf16x8 af[4], bfr[4];
    #pragma unroll
    for (int mi = 0; mi < 4; ++mi) af[mi]  = *(const bf16x8*)&As[(wm * 64 + mi * 16 + lc) * 40 + lg * 8];
    #pragma unroll
    for (int ni = 0; ni < 4; ++ni) bfr[ni] = *(const bf16x8*)&Bs[(wn * 64 + ni * 16 + lc) * 40 + lg * 8];
    #pragma unroll
    for (int mi = 0; mi < 4; ++mi)
      #pragma unroll
      for (int ni = 0; ni < 4; ++ni)
        acc[mi][ni] = MFMA16(af[mi], bfr[ni], acc[mi][ni]);
  }

  if constexpr (MODE == 1) {
    #pragma unroll
    for (int mi = 0; mi < 4; ++mi) {
      int mbase = m0 + wm * 64 + mi * 16 + lg * 4;
      #pragma unroll
      for (int ni = 0; ni < 4; ++ni) {
        int n = n0 + wn * 64 + ni * 16 + lc;
        #pragma unroll
        for (int r = 0; r < 4; ++r) o_f[(size_t)(mbase + r) * 256 + n] = acc[mi][ni][r];
      }
    }
  } else {
    #pragma unroll
    for (int mi = 0; mi < 4; ++mi) {
      int mbase = m0 + wm * 64 + mi * 16 + lg * 4;
      int bb = mbase >> 9, l = mbase & 511;
      #pragma unroll
      for (int ni = 0; ni < 4; ++ni) {
        int n = n0 + wn * 64 + ni * 16 + lc;
        if (n < 512) {   // uniform within each 16-lane group (16-aligned boundaries)
          u16* dst = (n < 256) ? o_q : o_k;
          int c = n & 255, hh = c >> 6, dd = c & 63;
          size_t base = (((size_t)bb * 4 + hh) * 512 + l) * 64 + dd;
          #pragma unroll
          for (int r = 0; r < 4; ++r) dst[base + (size_t)r * 64] = (u16)f2bf(acc[mi][ni][r]);
        } else {         // V transposed per head: vT[b][h][d][l], 4 consecutive l
          int c = n - 512, hh = c >> 6, dd = c & 63;
          ushort4 pk;
          pk.x = (u16)f2bf(acc[mi][ni][0]); pk.y = (u16)f2bf(acc[mi][ni][1]);
          pk.z = (u16)f2bf(acc[mi][ni][2]); pk.w = (u16)f2bf(acc[mi][ni][3]);
          *(ushort4*)&o_v[(((size_t)bb * 4 + hh) * 64 + dd) * 512 + l] = pk;
        }
      }
    }
  }
}

// ---------------------------------------------------------------------------
// Flash-style masked attention.  grid (8 qt, 128 b*4+h) x 256 (4 waves).
// Wave w owns 16 q-rows.  K-tile [64 keys][64 d], V-tile [64 d][64 keys] in LDS
// (rows padded to 72 elems = 144B = 9x16B -> conflict-free b128 reads).
// Online softmax on C/D fragments; P transposed via wave-private LDS.
__global__ __launch_bounds__(256) void attn(const u16* __restrict__ qb, const u16* __restrict__ kb,
                                            const u16* __restrict__ vtb, const u64* __restrict__ maskA,
                                            u16* __restrict__ ctxa) {
  __shared__ u16 Ks[64 * 72];
  __shared__ u16 Vs[64 * 72];
  __shared__ u16 Ps[4][16 * 72];
  const int qt = blockIdx.x, bh = blockIdx.y;
  const int b = bh >> 2, h = bh & 3;
  const int tid = threadIdx.x, lane = tid & 63, wid = tid >> 6;
  const int lg = lane >> 4, lc = lane & 15;

  // Q fragments (A-frag: row = lane&15, k-chunk = (lane>>4)*8), kept in regs
  const u16* qg = qb + ((size_t)bh * 512 + qt * 64 + wid * 16 + lc) * 64;
  bf16x8 aq0 = *(const bf16x8*)(qg + lg * 8);
  bf16x8 aq1 = *(const bf16x8*)(qg + 32 + lg * 8);

  float mrun[4], lrun[4];
  f32x4 acco[4] = {};
  #pragma unroll
  for (int r = 0; r < 4; ++r) { mrun[r] = -3.0e38f; lrun[r] = 0.f; }

  const u64* mrow = maskA + ((size_t)(h * 32 + b) * 512) * 8;
  const int qbase = qt * 64 + wid * 16 + lg * 4;

  const int srow = tid >> 2, spart = tid & 3;   // staging: 64 rows x 4x16-elem parts
  const u16* kg = kb + ((size_t)bh * 512 + srow) * 64 + spart * 16;
  const u16* vg = vtb + ((size_t)bh * 64 + srow) * 512 + spart * 16;
  const int sw = srow * 72 + spart * 16;

  for (int kt = 0; kt < 8; ++kt) {
    uint4 k0v = *(const uint4*)(kg + (size_t)kt * 4096);
    uint4 k1v = *(const uint4*)(kg + (size_t)kt * 4096 + 8);
    uint4 v0v = *(const uint4*)(vg + kt * 64);
    uint4 v1v = *(const uint4*)(vg + kt * 64 + 8);
    __syncthreads();
    *(uint4*)&Ks[sw] = k0v; *(uint4*)&Ks[sw + 8] = k1v;
    *(uint4*)&Vs[sw] = v0v; *(uint4*)&Vs[sw + 8] = v1v;
    __syncthreads();

    u64 mw[4];
    #pragma unroll
    for (int r = 0; r < 4; ++r) mw[r] = mrow[(size_t)(qbase + r) * 8 + kt];

    // S = Q K^T for 64 keys (4 x 16-key fragments)
    f32x4 sA[4];
    #pragma unroll
    for (int nf = 0; nf < 4; ++nf) {
      bf16x8 bk0 = *(const bf16x8*)&Ks[(nf * 16 + lc) * 72 + lg * 8];
      bf16x8 bk1 = *(const bf16x8*)&Ks[(nf * 16 + lc) * 72 + 32 + lg * 8];
      f32x4 z = {0.f, 0.f, 0.f, 0.f};
      z = MFMA16(aq0, bk0, z);
      z = MFMA16(aq1, bk1, z);
      sA[nf] = z;
    }
    // scale + mask + row-max
    float tmax[4];
    #pragma unroll
    for (int r = 0; r < 4; ++r) tmax[r] = -3.0e38f;
    #pragma unroll
    for (int nf = 0; nf < 4; ++nf)
      #pragma unroll
      for (int r = 0; r < 4; ++r) {
        float s = sA[nf][r] * 0.125f;
        bool ok = (mw[r] >> (nf * 16 + lc)) & 1ull;
        s = ok ? s : -3.0e38f;
        sA[nf][r] = s;
        tmax[r] = fmaxf(tmax[r], s);
      }
    #pragma unroll
    for (int off = 1; off < 16; off <<= 1)
      #pragma unroll
      for (int r = 0; r < 4; ++r) tmax[r] = fmaxf(tmax[r], __shfl_xor(tmax[r], off));

    float al[4], psum[4] = {0.f, 0.f, 0.f, 0.f};
    #pragma unroll
    for (int r = 0; r < 4; ++r) {
      float nm = fmaxf(mrun[r], tmax[r]);
      al[r] = __expf(mrun[r] - nm);
      mrun[r] = nm;
    }
    #pragma unroll
    for (int nf = 0; nf < 4; ++nf)
      #pragma unroll
      for (int r = 0; r < 4; ++r) {
        bool ok = (mw[r] >> (nf * 16 + lc)) & 1ull;
        float p = ok ? __expf(sA[nf][r] - mrun[r]) : 0.f;   // explicit 0: avoids exp(0)=1 on all-masked prefixes
        sA[nf][r] = p;
        psum[r] += p;
      }
    #pragma unroll
    for (int off = 1; off < 16; off <<= 1)
      #pragma unroll
      for (int r = 0; r < 4; ++r) psum[r] += __shfl_xor(psum[r], off);
    #pragma unroll
    for (int r = 0; r < 4; ++r) lrun[r] = lrun[r] * al[r] + psum[r];
    #pragma unroll
    for (int df = 0; df < 4; ++df)
      #pragma unroll
      for (int r = 0; r < 4; ++r) acco[df][r] = acco[df][r] * al[r];

    // P -> wave-private LDS (transpose C/D layout -> A-frag layout), then PV
    #pragma unroll
    for (int nf = 0; nf < 4; ++nf)
      #pragma unroll
      for (int r = 0; r < 4; ++r)
        Ps[wid][(lg * 4 + r) * 72 + nf * 16 + lc] = (u16)f2bf(sA[nf][r]);

    bf16x8 ap0 = *(const bf16x8*)&Ps[wid][lc * 72 + lg * 8];
    bf16x8 ap1 = *(const bf16x8*)&Ps[wid][lc * 72 + 32 + lg * 8];
    #pragma unroll
    for (int df = 0; df < 4; ++df) {
      bf16x8 bv0 = *(const bf16x8*)&Vs[(df * 16 + lc) * 72 + lg * 8];
      bf16x8 bv1 = *(const bf16x8*)&Vs[(df * 16 + lc) * 72 + 32 + lg * 8];
      acco[df] = MFMA16(ap0, bv0, acco[df]);
      acco[df] = MFMA16(ap1, bv1, acco[df]);
    }
  }

  // epilogue: normalize, write ctx augmented [hi | lo | hi]
  #pragma unroll
  for (int df = 0; df < 4; ++df)
    #pragma unroll
    for (int r = 0; r < 4; ++r) {
      float v = acco[df][r] / lrun[r];
      unsigned hi = f2bf(v);
      unsigned lo = f2bf(v - bf2f(hi));
      int rowq = qbase + r;
      size_t base = ((size_t)b * 512 + rowq) * 768;
      int c = h * 64 + df * 16 + lc;
      ctxa[base + c]       = (u16)hi;
      ctxa[base + 256 + c] = (u16)lo;
      ctxa[base + 512 + c] = (u16)hi;
    }
}

// ---------------------------------------------------------------------------
extern "C" void kernel_launch(void* const* d_in, const int* in_sizes, int n_in,
                              void* d_out, int out_size, void* d_ws, size_t ws_size,
                              hipStream_t stream) {
  const float* x     = (const float*)d_in[0];
  const int*   adj   = (const int*)d_in[1];
  const float* wqkv  = (const float*)d_in[2];
  const float* wproj = (const float*)d_in[3];
  char* ws = (char*)d_ws;
  u16* xb     = (u16*)(ws + OFF_XB);
  u16* wqkvb  = (u16*)(ws + OFF_WQKV);
  u16* wpa    = (u16*)(ws + OFF_WPA);
  u16* qb     = (u16*)(ws + OFF_QB);
  u16* kb     = (u16*)(ws + OFF_KB);
  u16* vtb    = (u16*)(ws + OFF_VTB);
  u16* ctxa   = (u16*)(ws + OFF_CTXA);
  u64* rowraw = (u64*)(ws + OFF_ROWR);
  u64* colraw = (u64*)(ws + OFF_COLR);
  u64* maskA  = (u64*)(ws + OFF_MASK);
  const size_t MSTRIDE = (size_t)32 * 512 * 8;   // u64 elems per head-mask

  cvt_bf16<<<dim3(2048), 256, 0, stream>>>(x, xb);
  cvt_bf16<<<dim3(96), 256, 0, stream>>>(wqkv, wqkvb);
  cvt_wproj_aug<<<dim3(256), 256, 0, stream>>>(wproj, wpa);
  bitpack_rows<<<dim3(32, 8), 256, 0, stream>>>(adj, rowraw, maskA);
  transpose_bits<<<dim3(32), 512, 0, stream>>>(rowraw, colraw, maskA + MSTRIDE);
  mask23<<<dim3(32, 8), 64, 0, stream>>>(rowraw, colraw, maskA + 2 * MSTRIDE, maskA + 3 * MSTRIDE);
  gemm_bt<0><<<dim3(128, 6), 256, 0, stream>>>(xb, wqkvb, 256, qb, kb, vtb, nullptr);
  attn<<<dim3(8, 128), 256, 0, stream>>>(qb, kb, vtb, maskA, ctxa);
  gemm_bt<1><<<dim3(128, 2), 256, 0, stream>>>(ctxa, wpa, 768, nullptr, nullptr, nullptr, (float*)d_out);
}

// Round 2
// 162.949 us; speedup vs baseline: 1.1814x; 1.1814x over previous
//
#include <hip/hip_runtime.h>

// ---------------------------------------------------------------------------
// MultiHeadAttention with relational-adjacency mask, MI355X (gfx950)
// B=32, L=512, DIM=256, NH=4, HD=64.  SCALE = 8.
//
// Pipeline:
//  cvt_bf16        : x, w_qkv -> bf16
//  cvt_wproj_aug   : w_proj -> [hi|hi|lo] bf16 (for split-precision out proj)
//  bitpack_rows    : adj -> row bitsets (a), + maskA[0] = a|eye   (ballot/word)
//  transpose_bits  : row bitsets -> col bitsets (aT), + maskA[1] = aT|eye
//  mask23          : maskA[2] = (aT@a != 0)|eye, maskA[3] = (a@aT != 0)|eye
//  gemm_bt<0>      : qkv = x @ w_qkv^T  (bf16 MFMA), scatter to q/k/vT layouts
//  attn            : flash-style masked attention, ctx -> [hi|lo|hi] bf16
//  gemm_bt<1>      : out = ctx_aug @ wproj_aug^T (split bf16 ~ f32 accuracy)
// ---------------------------------------------------------------------------

typedef unsigned long long u64;
typedef unsigned short u16;
typedef short bf16x8 __attribute__((ext_vector_type(8)));
typedef float f32x4 __attribute__((ext_vector_type(4)));

#define MFMA16(a, b, c) __builtin_amdgcn_mfma_f32_16x16x32_bf16((a), (b), (c), 0, 0, 0)

__device__ __forceinline__ unsigned f2bf(float f) {           // f32 -> bf16 (RNE)
  unsigned u = __float_as_uint(f);
  return (u + 0x7FFFu + ((u >> 16) & 1u)) >> 16;
}
__device__ __forceinline__ float bf2f(unsigned b) { return __uint_as_float(b << 16); }

// ---- workspace layout (bytes) ---------------------------------------------
#define OFF_XB    ((size_t)0)          // x bf16        [16384][256]   8,388,608
#define OFF_WQKV  ((size_t)8388608)    // w_qkv bf16    [768][256]       393,216
#define OFF_WPA   ((size_t)8781824)    // w_proj aug    [256][768]       393,216
#define OFF_QB    ((size_t)9175040)    // q bf16        [32][4][512][64] 8,388,608
#define OFF_KB    ((size_t)17563648)   // k bf16        [32][4][512][64] 8,388,608
#define OFF_VTB   ((size_t)25952256)   // vT bf16       [32][4][64][512] 8,388,608
#define OFF_CTXA  ((size_t)34340864)   // ctx aug bf16  [16384][768]    25,165,824
#define OFF_ROWR  ((size_t)59506688)   // row bitsets   [32][512][8]u64  1,048,576
#define OFF_COLR  ((size_t)60555264)   // col bitsets                    1,048,576
#define OFF_MASK  ((size_t)61603840)   // maskA[4][32][512][8]u64        4,194,304
// total 65,798,144 B (~62.8 MB)

// ---------------------------------------------------------------------------
// f32 -> bf16 conversion, 8 elems/thread (n must be multiple of 2048)
__global__ void cvt_bf16(const float* __restrict__ src, u16* __restrict__ dst) {
  size_t i = ((size_t)blockIdx.x * 256 + threadIdx.x) * 8;
  float4 a = *(const float4*)(src + i);
  float4 c = *(const float4*)(src + i + 4);
  uint4 o;
  o.x = f2bf(a.x) | (f2bf(a.y) << 16);
  o.y = f2bf(a.z) | (f2bf(a.w) << 16);
  o.z = f2bf(c.x) | (f2bf(c.y) << 16);
  o.w = f2bf(c.z) | (f2bf(c.w) << 16);
  *(uint4*)(dst + i) = o;
}

// w_proj [256][256] -> augmented [256][768] = [hi | hi | lo]
__global__ void cvt_wproj_aug(const float* __restrict__ wp, u16* __restrict__ wpa) {
  int idx = blockIdx.x * 256 + threadIdx.x;   // 0..65535
  int n = idx >> 8, k = idx & 255;
  float v = wp[idx];
  unsigned hi = f2bf(v);
  unsigned lo = f2bf(v - bf2f(hi));
  size_t base = (size_t)n * 768;
  wpa[base + k]       = (u16)hi;
  wpa[base + 256 + k] = (u16)hi;
  wpa[base + 512 + k] = (u16)lo;
}

// ---------------------------------------------------------------------------
// adj -> row bitsets.  bit = (adj==1 || adj>=9)  (a = binarized adjacency)
// grid 2048 x 512: block handles 8 rows; wave w produces word w of each row
// (one coalesced load + one ballot per word -> memory-throughput bound).
__global__ __launch_bounds__(512) void bitpack_rows(const int* __restrict__ adj,
                                                    u64* __restrict__ rowraw,
                                                    u64* __restrict__ maskA0) {
  int blk = blockIdx.x;                 // 64 blocks per batch b
  int b = blk >> 6, r0 = (blk & 63) * 8;
  int wave = threadIdx.x >> 6, lane = threadIdx.x & 63;
  #pragma unroll
  for (int rr = 0; rr < 8; ++rr) {
    int row = r0 + rr;
    int v = adj[((size_t)b * 512 + row) * 512 + wave * 64 + lane];
    u64 bal = __ballot(v == 1 || v >= 9);
    if (lane == 0) {
      size_t o = ((size_t)b * 512 + row) * 8 + wave;
      rowraw[o] = bal;
      maskA0[o] = bal | (((row >> 6) == wave) ? (1ull << (row & 63)) : 0ull);
    }
  }
}

// row bitsets -> col bitsets via ballot bit-transpose.  grid 32 x 512 (8 waves).
// Stage rowraw transposed in LDS (btr[word][row], 8B lane stride = conflict-
// free), then wave w builds all 8 words for cols w*64+lane; coalesced store.
__global__ __launch_bounds__(512) void transpose_bits(const u64* __restrict__ rowraw,
                                                      u64* __restrict__ colraw,
                                                      u64* __restrict__ maskA1) {
  __shared__ u64 btr[8 * 512];   // [word][row]
  int b = blockIdx.x, tid = threadIdx.x;
  {
    const u64* src = rowraw + (size_t)b * 4096 + (size_t)tid * 8;
    u64 r[8];
    #pragma unroll
    for (int w = 0; w < 8; ++w) r[w] = src[w];
    #pragma unroll
    for (int w = 0; w < 8; ++w) btr[w * 512 + tid] = r[w];
  }
  __syncthreads();
  int w = tid >> 6, lane = tid & 63;    // wave w handles cols w*64 .. w*64+63
  u64 words[8];
  #pragma unroll
  for (int wd = 0; wd < 8; ++wd) {
    u64 word = btr[w * 512 + wd * 64 + lane];   // rowraw[row=wd*64+lane], word w
    u64 mine = 0;
    #pragma unroll 1
    for (int c = 0; c < 64; ++c) {
      u64 bal = __ballot((word >> c) & 1ull);   // bit t = a[wd*64+t][w*64+c]
      if (lane == c) mine = bal;
    }
    words[wd] = mine;
  }
  int col = w * 64 + lane;
  u64* crow = colraw + (size_t)b * 4096 + (size_t)col * 8;
  u64* mrow = maskA1 + (size_t)b * 4096 + (size_t)col * 8;
  #pragma unroll
  for (int wd = 0; wd < 8; ++wd) crow[wd] = words[wd];
  words[w] |= (1ull << lane);                    // eye: col diag bit
  #pragma unroll
  for (int wd = 0; wd < 8; ++wd) mrow[wd] = words[wd];
}

// m2 = (aT@a != 0)|eye, m3 = (a@aT != 0)|eye.  grid (32 b, 8 qc) x 64
// m3row[q] = OR_{c: a[q][c]} colraw[c];  m2row[q] = OR_{r: a[r][q]} rowraw[r]
__global__ void mask23(const u64* __restrict__ rowraw, const u64* __restrict__ colraw,
                       u64* __restrict__ maskA2, u64* __restrict__ maskA3) {
  __shared__ u64 rb[4096];
  __shared__ u64 cbuf[4096];
  int b = blockIdx.x, qc = blockIdx.y, tid = threadIdx.x;   // 64 threads
  for (int i = tid; i < 4096; i += 64) {
    rb[i]   = rowraw[(size_t)b * 4096 + i];
    cbuf[i] = colraw[(size_t)b * 4096 + i];
  }
  __syncthreads();
  int q = qc * 64 + tid;
  u64 myrow[8], mycol[8];
  #pragma unroll
  for (int w = 0; w < 8; ++w) { myrow[w] = rb[q * 8 + w]; mycol[w] = cbuf[q * 8 + w]; }
  u64 a2[8] = {0, 0, 0, 0, 0, 0, 0, 0}, a3[8] = {0, 0, 0, 0, 0, 0, 0, 0};
  for (int c0 = 0; c0 < 512; c0 += 64) {
    for (int cc = 0; cc < 64; ++cc) {
      int c = c0 + cc;
      u64 p3 = 0ull - ((myrow[c >> 6] >> (c & 63)) & 1ull);
      u64 p2 = 0ull - ((mycol[c >> 6] >> (c & 63)) & 1ull);
      const u64* cr = &cbuf[c * 8];
      const u64* rr = &rb[c * 8];
      #pragma unroll
      for (int w = 0; w < 8; ++w) { a3[w] |= cr[w] & p3; a2[w] |= rr[w] & p2; }
    }
    u64 f = ~0ull;   // early exit: rows saturate to all-ones quickly at 50% density
    #pragma unroll
    for (int w = 0; w < 8; ++w) f &= (a2[w] & a3[w]);
    if (__all((int)(f == ~0ull))) break;
  }
  #pragma unroll
  for (int w = 0; w < 8; ++w) {
    u64 eye = ((q >> 6) == w) ? (1ull << (q & 63)) : 0ull;
    size_t o = ((size_t)b * 512 + q) * 8 + w;
    maskA2[o] = a2[w] | eye;
    maskA3[o] = a3[w] | eye;
  }
}

// ---------------------------------------------------------------------------
// GEMM  C[m][n] = sum_k A[m][k] * Bw[n][k]   (both row-major, K-contiguous)
// 128x128 tile, BK=32, 4 waves (2x2 of 64x64), 16x16x32 bf16 MFMA.
// LDS rows padded to 40 elems (80B = 5x16B -> conflict-free ds_read_b128).
// MODE 0: scatter epilogue -> q[b][h][l][d], k[b][h][l][d], vT[b][h][d][l]
// MODE 1: float epilogue  -> o_f[m][n]  (N=256)
template <int MODE>
__global__ __launch_bounds__(256) void gemm_bt(const u16* __restrict__ A,
                                               const u16* __restrict__ Bw, int Kd,
                                               u16* __restrict__ o_q, u16* __restrict__ o_k,
                                               u16* __restrict__ o_v, float* __restrict__ o_f) {
  __shared__ u16 As[128 * 40];
  __shared__ u16 Bs[128 * 40];
  const int tid = threadIdx.x;
  const int lane = tid & 63, wid = tid >> 6;
  const int lg = lane >> 4, lc = lane & 15;
  const int wm = wid >> 1, wn = wid & 1;
  const int m0 = blockIdx.x * 128, n0 = blockIdx.y * 128;
  f32x4 acc[4][4] = {};
  const int srow = tid >> 1, half = tid & 1;
  const u16* ag = A + (size_t)(m0 + srow) * Kd + half * 16;
  const u16* bg = Bw + (size_t)(n0 + srow) * Kd + half * 16;
  const int lw = srow * 40 + half * 16;

  for (int k0 = 0; k0 < Kd; k0 += 32) {
    uint4 av0 = *(const uint4*)(ag + k0);
    uint4 av1 = *(const uint4*)(ag + k0 + 8);
    uint4 bv0 = *(const uint4*)(bg + k0);
    uint4 bv1 = *(const uint4*)(bg + k0 + 8);
    __syncthreads();
    *(uint4*)&As[lw] = av0; *(uint4*)&As[lw + 8] = av1;
    *(uint4*)&Bs[lw] = bv0; *(uint4*)&Bs[lw + 8] = bv1;
    __syncthreads();
    bf16x8 af[4], bfr[4];
    #pragma unroll
    for (int mi = 0; mi < 4; ++mi) af[mi]  = *(const bf16x8*)&As[(wm * 64 + mi * 16 + lc) * 40 + lg * 8];
    #pragma unroll
    for (int ni = 0; ni < 4; ++ni) bfr[ni] = *(const bf16x8*)&Bs[(wn * 64 + ni * 16 + lc) * 40 + lg * 8];
    #pragma unroll
    for (int mi = 0; mi < 4; ++mi)
      #pragma unroll
      for (int ni = 0; ni < 4; ++ni)
        acc[mi][ni] = MFMA16(af[mi], bfr[ni], acc[mi][ni]);
  }

  if constexpr (MODE == 1) {
    #pragma unroll
    for (int mi = 0; mi < 4; ++mi) {
      int mbase = m0 + wm * 64 + mi * 16 + lg * 4;
      #pragma unroll
      for (int ni = 0; ni < 4; ++ni) {
        int n = n0 + wn * 64 + ni * 16 + lc;
        #pragma unroll
        for (int r = 0; r < 4; ++r) o_f[(size_t)(mbase + r) * 256 + n] = acc[mi][ni][r];
      }
    }
  } else {
    #pragma unroll
    for (int mi = 0; mi < 4; ++mi) {
      int mbase = m0 + wm * 64 + mi * 16 + lg * 4;
      int bb = mbase >> 9, l = mbase & 511;
      #pragma unroll
      for (int ni = 0; ni < 4; ++ni) {
        int n = n0 + wn * 64 + ni * 16 + lc;
        if (n < 512) {   // uniform within each 16-lane group (16-aligned boundaries)
          u16* dst = (n < 256) ? o_q : o_k;
          int c = n & 255, hh = c >> 6, dd = c & 63;
          size_t base = (((size_t)bb * 4 + hh) * 512 + l) * 64 + dd;
          #pragma unroll
          for (int r = 0; r < 4; ++r) dst[base + (size_t)r * 64] = (u16)f2bf(acc[mi][ni][r]);
        } else {         // V transposed per head: vT[b][h][d][l], 4 consecutive l
          int c = n - 512, hh = c >> 6, dd = c & 63;
          ushort4 pk;
          pk.x = (u16)f2bf(acc[mi][ni][0]); pk.y = (u16)f2bf(acc[mi][ni][1]);
          pk.z = (u16)f2bf(acc[mi][ni][2]); pk.w = (u16)f2bf(acc[mi][ni][3]);
          *(ushort4*)&o_v[(((size_t)bb * 4 + hh) * 64 + dd) * 512 + l] = pk;
        }
      }
    }
  }
}

// ---------------------------------------------------------------------------
// Flash-style masked attention.  grid (8 qt, 128 b*4+h) x 256 (4 waves).
// Wave w owns 16 q-rows.  K-tile [64 keys][64 d], V-tile [64 d][64 keys] in LDS
// (rows padded to 72 elems = 144B = 9x16B -> conflict-free b128 reads).
// Online softmax on C/D fragments; P transposed via wave-private LDS.
__global__ __launch_bounds__(256) void attn(const u16* __restrict__ qb, const u16* __restrict__ kb,
                                            const u16* __restrict__ vtb, const u64* __restrict__ maskA,
                                            u16* __restrict__ ctxa) {
  __shared__ u16 Ks[64 * 72];
  __shared__ u16 Vs[64 * 72];
  __shared__ u16 Ps[4][16 * 72];
  const int qt = blockIdx.x, bh = blockIdx.y;
  const int b = bh >> 2, h = bh & 3;
  const int tid = threadIdx.x, lane = tid & 63, wid = tid >> 6;
  const int lg = lane >> 4, lc = lane & 15;

  // Q fragments (A-frag: row = lane&15, k-chunk = (lane>>4)*8), kept in regs
  const u16* qg = qb + ((size_t)bh * 512 + qt * 64 + wid * 16 + lc) * 64;
  bf16x8 aq0 = *(const bf16x8*)(qg + lg * 8);
  bf16x8 aq1 = *(const bf16x8*)(qg + 32 + lg * 8);

  float mrun[4], lrun[4];
  f32x4 acco[4] = {};
  #pragma unroll
  for (int r = 0; r < 4; ++r) { mrun[r] = -3.0e38f; lrun[r] = 0.f; }

  const u64* mrow = maskA + ((size_t)(h * 32 + b) * 512) * 8;
  const int qbase = qt * 64 + wid * 16 + lg * 4;

  const int srow = tid >> 2, spart = tid & 3;   // staging: 64 rows x 4x16-elem parts
  const u16* kg = kb + ((size_t)bh * 512 + srow) * 64 + spart * 16;
  const u16* vg = vtb + ((size_t)bh * 64 + srow) * 512 + spart * 16;
  const int sw = srow * 72 + spart * 16;

  for (int kt = 0; kt < 8; ++kt) {
    uint4 k0v = *(const uint4*)(kg + (size_t)kt * 4096);
    uint4 k1v = *(const uint4*)(kg + (size_t)kt * 4096 + 8);
    uint4 v0v = *(const uint4*)(vg + kt * 64);
    uint4 v1v = *(const uint4*)(vg + kt * 64 + 8);
    __syncthreads();
    *(uint4*)&Ks[sw] = k0v; *(uint4*)&Ks[sw + 8] = k1v;
    *(uint4*)&Vs[sw] = v0v; *(uint4*)&Vs[sw + 8] = v1v;
    __syncthreads();

    u64 mw[4];
    #pragma unroll
    for (int r = 0; r < 4; ++r) mw[r] = mrow[(size_t)(qbase + r) * 8 + kt];

    // S = Q K^T for 64 keys (4 x 16-key fragments)
    f32x4 sA[4];
    #pragma unroll
    for (int nf = 0; nf < 4; ++nf) {
      bf16x8 bk0 = *(const bf16x8*)&Ks[(nf * 16 + lc) * 72 + lg * 8];
      bf16x8 bk1 = *(const bf16x8*)&Ks[(nf * 16 + lc) * 72 + 32 + lg * 8];
      f32x4 z = {0.f, 0.f, 0.f, 0.f};
      z = MFMA16(aq0, bk0, z);
      z = MFMA16(aq1, bk1, z);
      sA[nf] = z;
    }
    // scale + mask + row-max
    float tmax[4];
    #pragma unroll
    for (int r = 0; r < 4; ++r) tmax[r] = -3.0e38f;
    #pragma unroll
    for (int nf = 0; nf < 4; ++nf)
      #pragma unroll
      for (int r = 0; r < 4; ++r) {
        float s = sA[nf][r] * 0.125f;
        bool ok = (mw[r] >> (nf * 16 + lc)) & 1ull;
        s = ok ? s : -3.0e38f;
        sA[nf][r] = s;
        tmax[r] = fmaxf(tmax[r], s);
      }
    #pragma unroll
    for (int off = 1; off < 16; off <<= 1)
      #pragma unroll
      for (int r = 0; r < 4; ++r) tmax[r] = fmaxf(tmax[r], __shfl_xor(tmax[r], off));

    float al[4], psum[4] = {0.f, 0.f, 0.f, 0.f};
    #pragma unroll
    for (int r = 0; r < 4; ++r) {
      float nm = fmaxf(mrun[r], tmax[r]);
      al[r] = __expf(mrun[r] - nm);
      mrun[r] = nm;
    }
    #pragma unroll
    for (int nf = 0; nf < 4; ++nf)
      #pragma unroll
      for (int r = 0; r < 4; ++r) {
        bool ok = (mw[r] >> (nf * 16 + lc)) & 1ull;
        float p = ok ? __expf(sA[nf][r] - mrun[r]) : 0.f;   // explicit 0: avoids exp(0)=1 on all-masked prefixes
        sA[nf][r] = p;
        psum[r] += p;
      }
    #pragma unroll
    for (int off = 1; off < 16; off <<= 1)
      #pragma unroll
      for (int r = 0; r < 4; ++r) psum[r] += __shfl_xor(psum[r], off);
    #pragma unroll
    for (int r = 0; r < 4; ++r) lrun[r] = lrun[r] * al[r] + psum[r];
    #pragma unroll
    for (int df = 0; df < 4; ++df)
      #pragma unroll
      for (int r = 0; r < 4; ++r) acco[df][r] = acco[df][r] * al[r];

    // P -> wave-private LDS (transpose C/D layout -> A-frag layout), then PV
    #pragma unroll
    for (int nf = 0; nf < 4; ++nf)
      #pragma unroll
      for (int r = 0; r < 4; ++r)
        Ps[wid][(lg * 4 + r) * 72 + nf * 16 + lc] = (u16)f2bf(sA[nf][r]);

    bf16x8 ap0 = *(const bf16x8*)&Ps[wid][lc * 72 + lg * 8];
    bf16x8 ap1 = *(const bf16x8*)&Ps[wid][lc * 72 + 32 + lg * 8];
    #pragma unroll
    for (int df = 0; df < 4; ++df) {
      bf16x8 bv0 = *(const bf16x8*)&Vs[(df * 16 + lc) * 72 + lg * 8];
      bf16x8 bv1 = *(const bf16x8*)&Vs[(df * 16 + lc) * 72 + 32 + lg * 8];
      acco[df] = MFMA16(ap0, bv0, acco[df]);
      acco[df] = MFMA16(ap1, bv1, acco[df]);
    }
  }

  // epilogue: normalize, write ctx augmented [hi | lo | hi]
  #pragma unroll
  for (int df = 0; df < 4; ++df)
    #pragma unroll
    for (int r = 0; r < 4; ++r) {
      float v = acco[df][r] / lrun[r];
      unsigned hi = f2bf(v);
      unsigned lo = f2bf(v - bf2f(hi));
      int rowq = qbase + r;
      size_t base = ((size_t)b * 512 + rowq) * 768;
      int c = h * 64 + df * 16 + lc;
      ctxa[base + c]       = (u16)hi;
      ctxa[base + 256 + c] = (u16)lo;
      ctxa[base + 512 + c] = (u16)hi;
    }
}

// ---------------------------------------------------------------------------
extern "C" void kernel_launch(void* const* d_in, const int* in_sizes, int n_in,
                              void* d_out, int out_size, void* d_ws, size_t ws_size,
                              hipStream_t stream) {
  const float* x     = (const float*)d_in[0];
  const int*   adj   = (const int*)d_in[1];
  const float* wqkv  = (const float*)d_in[2];
  const float* wproj = (const float*)d_in[3];
  char* ws = (char*)d_ws;
  u16* xb     = (u16*)(ws + OFF_XB);
  u16* wqkvb  = (u16*)(ws + OFF_WQKV);
  u16* wpa    = (u16*)(ws + OFF_WPA);
  u16* qb     = (u16*)(ws + OFF_QB);
  u16* kb     = (u16*)(ws + OFF_KB);
  u16* vtb    = (u16*)(ws + OFF_VTB);
  u16* ctxa   = (u16*)(ws + OFF_CTXA);
  u64* rowraw = (u64*)(ws + OFF_ROWR);
  u64* colraw = (u64*)(ws + OFF_COLR);
  u64* maskA  = (u64*)(ws + OFF_MASK);
  const size_t MSTRIDE = (size_t)32 * 512 * 8;   // u64 elems per head-mask

  cvt_bf16<<<dim3(2048), 256, 0, stream>>>(x, xb);
  cvt_bf16<<<dim3(96), 256, 0, stream>>>(wqkv, wqkvb);
  cvt_wproj_aug<<<dim3(256), 256, 0, stream>>>(wproj, wpa);
  bitpack_rows<<<dim3(2048), 512, 0, stream>>>(adj, rowraw, maskA);
  transpose_bits<<<dim3(32), 512, 0, stream>>>(rowraw, colraw, maskA + MSTRIDE);
  mask23<<<dim3(32, 8), 64, 0, stream>>>(rowraw, colraw, maskA + 2 * MSTRIDE, maskA + 3 * MSTRIDE);
  gemm_bt<0><<<dim3(128, 6), 256, 0, stream>>>(xb, wqkvb, 256, qb, kb, vtb, nullptr);
  attn<<<dim3(8, 128), 256, 0, stream>>>(qb, kb, vtb, maskA, ctxa);
  gemm_bt<1><<<dim3(128, 2), 256, 0, stream>>>(ctxa, wpa, 768, nullptr, nullptr, nullptr, (float*)d_out);
}

// Round 3
// 149.830 us; speedup vs baseline: 1.2848x; 1.0876x over previous
//
#include <hip/hip_runtime.h>

// ---------------------------------------------------------------------------
// MultiHeadAttention with relational-adjacency mask, MI355X (gfx950)
// B=32, L=512, DIM=256, NH=4, HD=64.  SCALE = 8.
//
// Pipeline:
//  cvt_bf16        : x, w_qkv -> bf16
//  cvt_wproj_aug   : w_proj -> [hi|hi|lo] bf16 (for split-precision out proj)
//  bitpack_rows    : adj -> row bitsets (a), + maskA[0] = a|eye   (ballot/word)
//  transpose_bits  : row bitsets -> col bitsets (aT), + maskA[1] = aT|eye
//  mask23          : maskA[2] = (aT@a != 0)|eye, maskA[3] = (a@aT != 0)|eye
//  gemm_bt<0>      : qkv = x @ w_qkv^T  (bf16 MFMA), scatter to q/k/vT layouts
//  attn            : flash attention, swapped QK^T (S^T), per-lane softmax
//  gemm_bt<1>      : out = ctx_aug @ wproj_aug^T (split bf16 ~ f32 accuracy)
// ---------------------------------------------------------------------------

typedef unsigned long long u64;
typedef unsigned short u16;
typedef short bf16x8 __attribute__((ext_vector_type(8)));
typedef float f32x4 __attribute__((ext_vector_type(4)));

#define MFMA16(a, b, c) __builtin_amdgcn_mfma_f32_16x16x32_bf16((a), (b), (c), 0, 0, 0)

__device__ __forceinline__ unsigned f2bf(float f) {           // f32 -> bf16 (RNE)
  unsigned u = __float_as_uint(f);
  return (u + 0x7FFFu + ((u >> 16) & 1u)) >> 16;
}
__device__ __forceinline__ float bf2f(unsigned b) { return __uint_as_float(b << 16); }

// ---- workspace layout (bytes) ---------------------------------------------
#define OFF_XB    ((size_t)0)          // x bf16        [16384][256]   8,388,608
#define OFF_WQKV  ((size_t)8388608)    // w_qkv bf16    [768][256]       393,216
#define OFF_WPA   ((size_t)8781824)    // w_proj aug    [256][768]       393,216
#define OFF_QB    ((size_t)9175040)    // q bf16        [32][4][512][64] 8,388,608
#define OFF_KB    ((size_t)17563648)   // k bf16        [32][4][512][64] 8,388,608
#define OFF_VTB   ((size_t)25952256)   // vT bf16       [32][4][64][512] 8,388,608
#define OFF_CTXA  ((size_t)34340864)   // ctx aug bf16  [16384][768]    25,165,824
#define OFF_ROWR  ((size_t)59506688)   // row bitsets   [32][512][8]u64  1,048,576
#define OFF_COLR  ((size_t)60555264)   // col bitsets                    1,048,576
#define OFF_MASK  ((size_t)61603840)   // maskA[4][32][512][8]u64        4,194,304
// total 65,798,144 B (~62.8 MB)

// ---------------------------------------------------------------------------
// f32 -> bf16 conversion, 8 elems/thread (n must be multiple of 2048)
__global__ void cvt_bf16(const float* __restrict__ src, u16* __restrict__ dst) {
  size_t i = ((size_t)blockIdx.x * 256 + threadIdx.x) * 8;
  float4 a = *(const float4*)(src + i);
  float4 c = *(const float4*)(src + i + 4);
  uint4 o;
  o.x = f2bf(a.x) | (f2bf(a.y) << 16);
  o.y = f2bf(a.z) | (f2bf(a.w) << 16);
  o.z = f2bf(c.x) | (f2bf(c.y) << 16);
  o.w = f2bf(c.z) | (f2bf(c.w) << 16);
  *(uint4*)(dst + i) = o;
}

// w_proj [256][256] -> augmented [256][768] = [hi | hi | lo]
__global__ void cvt_wproj_aug(const float* __restrict__ wp, u16* __restrict__ wpa) {
  int idx = blockIdx.x * 256 + threadIdx.x;   // 0..65535
  int n = idx >> 8, k = idx & 255;
  float v = wp[idx];
  unsigned hi = f2bf(v);
  unsigned lo = f2bf(v - bf2f(hi));
  size_t base = (size_t)n * 768;
  wpa[base + k]       = (u16)hi;
  wpa[base + 256 + k] = (u16)hi;
  wpa[base + 512 + k] = (u16)lo;
}

// ---------------------------------------------------------------------------
// adj -> row bitsets.  bit = (adj==1 || adj>=9)  (a = binarized adjacency)
// grid 2048 x 512: block handles 8 rows; wave w produces word w of each row.
__global__ __launch_bounds__(512) void bitpack_rows(const int* __restrict__ adj,
                                                    u64* __restrict__ rowraw,
                                                    u64* __restrict__ maskA0) {
  int blk = blockIdx.x;                 // 64 blocks per batch b
  int b = blk >> 6, r0 = (blk & 63) * 8;
  int wave = threadIdx.x >> 6, lane = threadIdx.x & 63;
  #pragma unroll
  for (int rr = 0; rr < 8; ++rr) {
    int row = r0 + rr;
    int v = adj[((size_t)b * 512 + row) * 512 + wave * 64 + lane];
    u64 bal = __ballot(v == 1 || v >= 9);
    if (lane == 0) {
      size_t o = ((size_t)b * 512 + row) * 8 + wave;
      rowraw[o] = bal;
      maskA0[o] = bal | (((row >> 6) == wave) ? (1ull << (row & 63)) : 0ull);
    }
  }
}

// row bitsets -> col bitsets via ballot bit-transpose.  grid 32 x 512 (8 waves).
__global__ __launch_bounds__(512) void transpose_bits(const u64* __restrict__ rowraw,
                                                      u64* __restrict__ colraw,
                                                      u64* __restrict__ maskA1) {
  __shared__ u64 btr[8 * 512];   // [word][row]
  int b = blockIdx.x, tid = threadIdx.x;
  {
    const u64* src = rowraw + (size_t)b * 4096 + (size_t)tid * 8;
    u64 r[8];
    #pragma unroll
    for (int w = 0; w < 8; ++w) r[w] = src[w];
    #pragma unroll
    for (int w = 0; w < 8; ++w) btr[w * 512 + tid] = r[w];
  }
  __syncthreads();
  int w = tid >> 6, lane = tid & 63;    // wave w handles cols w*64 .. w*64+63
  u64 words[8];
  #pragma unroll
  for (int wd = 0; wd < 8; ++wd) {
    u64 word = btr[w * 512 + wd * 64 + lane];   // rowraw[row=wd*64+lane], word w
    u64 mine = 0;
    #pragma unroll 1
    for (int c = 0; c < 64; ++c) {
      u64 bal = __ballot((word >> c) & 1ull);   // bit t = a[wd*64+t][w*64+c]
      if (lane == c) mine = bal;
    }
    words[wd] = mine;
  }
  int col = w * 64 + lane;
  u64* crow = colraw + (size_t)b * 4096 + (size_t)col * 8;
  u64* mrow = maskA1 + (size_t)b * 4096 + (size_t)col * 8;
  #pragma unroll
  for (int wd = 0; wd < 8; ++wd) crow[wd] = words[wd];
  words[w] |= (1ull << lane);                    // eye: col diag bit
  #pragma unroll
  for (int wd = 0; wd < 8; ++wd) mrow[wd] = words[wd];
}

// m2 = (aT@a != 0)|eye, m3 = (a@aT != 0)|eye.  grid (32 b, 8 qc) x 64
__global__ void mask23(const u64* __restrict__ rowraw, const u64* __restrict__ colraw,
                       u64* __restrict__ maskA2, u64* __restrict__ maskA3) {
  __shared__ u64 rb[4096];
  __shared__ u64 cbuf[4096];
  int b = blockIdx.x, qc = blockIdx.y, tid = threadIdx.x;   // 64 threads
  for (int i = tid; i < 4096; i += 64) {
    rb[i]   = rowraw[(size_t)b * 4096 + i];
    cbuf[i] = colraw[(size_t)b * 4096 + i];
  }
  __syncthreads();
  int q = qc * 64 + tid;
  u64 myrow[8], mycol[8];
  #pragma unroll
  for (int w = 0; w < 8; ++w) { myrow[w] = rb[q * 8 + w]; mycol[w] = cbuf[q * 8 + w]; }
  u64 a2[8] = {0, 0, 0, 0, 0, 0, 0, 0}, a3[8] = {0, 0, 0, 0, 0, 0, 0, 0};
  for (int c0 = 0; c0 < 512; c0 += 64) {
    for (int cc = 0; cc < 64; ++cc) {
      int c = c0 + cc;
      u64 p3 = 0ull - ((myrow[c >> 6] >> (c & 63)) & 1ull);
      u64 p2 = 0ull - ((mycol[c >> 6] >> (c & 63)) & 1ull);
      const u64* cr = &cbuf[c * 8];
      const u64* rr = &rb[c * 8];
      #pragma unroll
      for (int w = 0; w < 8; ++w) { a3[w] |= cr[w] & p3; a2[w] |= rr[w] & p2; }
    }
    u64 f = ~0ull;   // early exit: rows saturate to all-ones quickly at 50% density
    #pragma unroll
    for (int w = 0; w < 8; ++w) f &= (a2[w] & a3[w]);
    if (__all((int)(f == ~0ull))) break;
  }
  #pragma unroll
  for (int w = 0; w < 8; ++w) {
    u64 eye = ((q >> 6) == w) ? (1ull << (q & 63)) : 0ull;
    size_t o = ((size_t)b * 512 + q) * 8 + w;
    maskA2[o] = a2[w] | eye;
    maskA3[o] = a3[w] | eye;
  }
}

// ---------------------------------------------------------------------------
// GEMM  C[m][n] = sum_k A[m][k] * Bw[n][k]   (both row-major, K-contiguous)
// 128x128 tile, BK=32, 4 waves (2x2 of 64x64), 16x16x32 bf16 MFMA.
template <int MODE>
__global__ __launch_bounds__(256) void gemm_bt(const u16* __restrict__ A,
                                               const u16* __restrict__ Bw, int Kd,
                                               u16* __restrict__ o_q, u16* __restrict__ o_k,
                                               u16* __restrict__ o_v, float* __restrict__ o_f) {
  __shared__ u16 As[128 * 40];
  __shared__ u16 Bs[128 * 40];
  const int tid = threadIdx.x;
  const int lane = tid & 63, wid = tid >> 6;
  const int lg = lane >> 4, lc = lane & 15;
  const int wm = wid >> 1, wn = wid & 1;
  const int m0 = blockIdx.x * 128, n0 = blockIdx.y * 128;
  f32x4 acc[4][4] = {};
  const int srow = tid >> 1, half = tid & 1;
  const u16* ag = A + (size_t)(m0 + srow) * Kd + half * 16;
  const u16* bg = Bw + (size_t)(n0 + srow) * Kd + half * 16;
  const int lw = srow * 40 + half * 16;

  for (int k0 = 0; k0 < Kd; k0 += 32) {
    uint4 av0 = *(const uint4*)(ag + k0);
    uint4 av1 = *(const uint4*)(ag + k0 + 8);
    uint4 bv0 = *(const uint4*)(bg + k0);
    uint4 bv1 = *(const uint4*)(bg + k0 + 8);
    __syncthreads();
    *(uint4*)&As[lw] = av0; *(uint4*)&As[lw + 8] = av1;
    *(uint4*)&Bs[lw] = bv0; *(uint4*)&Bs[lw + 8] = bv1;
    __syncthreads();
    bf16x8 af[4], bfr[4];
    #pragma unroll
    for (int mi = 0; mi < 4; ++mi) af[mi]  = *(const bf16x8*)&As[(wm * 64 + mi * 16 + lc) * 40 + lg * 8];
    #pragma unroll
    for (int ni = 0; ni < 4; ++ni) bfr[ni] = *(const bf16x8*)&Bs[(wn * 64 + ni * 16 + lc) * 40 + lg * 8];
    #pragma unroll
    for (int mi = 0; mi < 4; ++mi)
      #pragma unroll
      for (int ni = 0; ni < 4; ++ni)
        acc[mi][ni] = MFMA16(af[mi], bfr[ni], acc[mi][ni]);
  }

  if constexpr (MODE == 1) {
    #pragma unroll
    for (int mi = 0; mi < 4; ++mi) {
      int mbase = m0 + wm * 64 + mi * 16 + lg * 4;
      #pragma unroll
      for (int ni = 0; ni < 4; ++ni) {
        int n = n0 + wn * 64 + ni * 16 + lc;
        #pragma unroll
        for (int r = 0; r < 4; ++r) o_f[(size_t)(mbase + r) * 256 + n] = acc[mi][ni][r];
      }
    }
  } else {
    #pragma unroll
    for (int mi = 0; mi < 4; ++mi) {
      int mbase = m0 + wm * 64 + mi * 16 + lg * 4;
      int bb = mbase >> 9, l = mbase & 511;
      #pragma unroll
      for (int ni = 0; ni < 4; ++ni) {
        int n = n0 + wn * 64 + ni * 16 + lc;
        if (n < 512) {   // uniform within each 16-lane group (16-aligned boundaries)
          u16* dst = (n < 256) ? o_q : o_k;
          int c = n & 255, hh = c >> 6, dd = c & 63;
          size_t base = (((size_t)bb * 4 + hh) * 512 + l) * 64 + dd;
          #pragma unroll
          for (int r = 0; r < 4; ++r) dst[base + (size_t)r * 64] = (u16)f2bf(acc[mi][ni][r]);
        } else {         // V transposed per head: vT[b][h][d][l], 4 consecutive l
          int c = n - 512, hh = c >> 6, dd = c & 63;
          ushort4 pk;
          pk.x = (u16)f2bf(acc[mi][ni][0]); pk.y = (u16)f2bf(acc[mi][ni][1]);
          pk.z = (u16)f2bf(acc[mi][ni][2]); pk.w = (u16)f2bf(acc[mi][ni][3]);
          *(ushort4*)&o_v[(((size_t)bb * 4 + hh) * 64 + dd) * 512 + l] = pk;
        }
      }
    }
  }
}

// ---------------------------------------------------------------------------
// Flash attention v2: grid (4 qt, 128 b*4+h) x 512 (8 waves, 128 q-rows/block).
// Swapped QK^T: S^T = mfma(K_frag, Q_frag) -> lane holds 16 P-values of ONE
// q-row (q = lane&15); softmax is 15 in-reg max/add + 2 shfl_xor; m/l scalar.
// Masked entries use -3e38 sentinel; all-masked tiles self-heal (next valid
// tile rescales by exp2(-huge)=0; diagonal eye guarantees a valid key).
// P^T -> A-frag via wave-private LDS (4 x ds_write_b64 + 2 x ds_read_b128).
__global__ __launch_bounds__(512, 4) void attn(const u16* __restrict__ qb, const u16* __restrict__ kb,
                                               const u16* __restrict__ vtb, const u64* __restrict__ maskA,
                                               u16* __restrict__ ctxa) {
  __shared__ u16 Ks[64 * 72];
  __shared__ u16 Vs[64 * 72];
  __shared__ u16 Ps[8][16 * 72];
  const int qt = blockIdx.x, bh = blockIdx.y;
  const int b = bh >> 2, h = bh & 3;
  const int tid = threadIdx.x, lane = tid & 63, wid = tid >> 6;
  const int lg = lane >> 4, lc = lane & 15;
  const float SC = 0.125f * 1.4426950408889634f;   // /sqrt(64) * log2(e)

  // Q as B-frag (col = q = lc, inner = d), kept in regs
  const u16* qg = qb + ((size_t)bh * 512 + qt * 128 + wid * 16 + lc) * 64;
  bf16x8 q0 = *(const bf16x8*)(qg + lg * 8);
  bf16x8 q1 = *(const bf16x8*)(qg + 32 + lg * 8);

  float mrun = -3.0e38f, lrun = 0.f;
  f32x4 acco[4] = {};

  // mask row for this lane's q-row
  const u64* mrow = maskA + ((size_t)(h * 32 + b) * 512 + qt * 128 + wid * 16 + lc) * 8;

  // staging: 512 threads, 1 x b128 each for K and V tiles (64x64 u16)
  const int srow = tid >> 3, scol = (tid & 7) * 8;
  const u16* kg = kb + ((size_t)bh * 512 + srow) * 64 + scol;
  const u16* vg = vtb + ((size_t)bh * 64 + srow) * 512 + scol;
  const int skw = srow * 72 + scol;

  for (int kt = 0; kt < 8; ++kt) {
    uint4 kv = *(const uint4*)(kg + (size_t)kt * 4096);
    uint4 vv = *(const uint4*)(vg + kt * 64);
    __syncthreads();
    *(uint4*)&Ks[skw] = kv;
    *(uint4*)&Vs[skw] = vv;
    __syncthreads();

    u64 mw = mrow[kt] >> (lg * 4);   // bit (nf*16 + r) = key nf*16+lg*4+r

    // S^T = K Q^T: lane holds keys {nf*16+lg*4+r}, q-row = lc
    f32x4 sT[4];
    #pragma unroll
    for (int nf = 0; nf < 4; ++nf) {
      bf16x8 ak0 = *(const bf16x8*)&Ks[(nf * 16 + lc) * 72 + lg * 8];
      bf16x8 ak1 = *(const bf16x8*)&Ks[(nf * 16 + lc) * 72 + 32 + lg * 8];
      f32x4 z = {0.f, 0.f, 0.f, 0.f};
      z = MFMA16(ak0, q0, z);
      z = MFMA16(ak1, q1, z);
      sT[nf] = z;
    }

    // scale (log2 domain) + mask + per-lane max over 16, then 2-shuffle reduce
    float p[4][4];
    float tm = -3.0e38f;
    #pragma unroll
    for (int nf = 0; nf < 4; ++nf)
      #pragma unroll
      for (int r = 0; r < 4; ++r) {
        float s = sT[nf][r] * SC;
        bool ok = (mw >> (nf * 16 + r)) & 1ull;
        s = ok ? s : -3.0e38f;
        p[nf][r] = s;
        tm = fmaxf(tm, s);
      }
    tm = fmaxf(tm, __shfl_xor(tm, 16));
    tm = fmaxf(tm, __shfl_xor(tm, 32));

    float nm = fmaxf(mrun, tm);
    float al = exp2f(mrun - nm);
    mrun = nm;

    float ps = 0.f;
    #pragma unroll
    for (int nf = 0; nf < 4; ++nf)
      #pragma unroll
      for (int r = 0; r < 4; ++r) {
        float e = exp2f(p[nf][r] - nm);   // masked: -3e38-nm -> exp2 -> 0 (or 1 if tile all-masked; self-heals)
        p[nf][r] = e;
        ps += e;
      }
    ps += __shfl_xor(ps, 16);
    ps += __shfl_xor(ps, 32);
    lrun = lrun * al + ps;

    // P^T -> Ps[q=lc][k]  (4 x ds_write_b64, wave-private)
    #pragma unroll
    for (int nf = 0; nf < 4; ++nf) {
      ushort4 w;
      w.x = (u16)f2bf(p[nf][0]); w.y = (u16)f2bf(p[nf][1]);
      w.z = (u16)f2bf(p[nf][2]); w.w = (u16)f2bf(p[nf][3]);
      *(ushort4*)&Ps[wid][lc * 72 + nf * 16 + lg * 4] = w;
    }

    // rescale acco rows (output rows q = lg*4+r live in other lanes' stats)
    float alr[4];
    #pragma unroll
    for (int r = 0; r < 4; ++r) alr[r] = __shfl(al, (lane & 48) | (lg * 4 + r));
    #pragma unroll
    for (int df = 0; df < 4; ++df)
      #pragma unroll
      for (int r = 0; r < 4; ++r) acco[df][r] *= alr[r];

    // PV: A-frag P (row=q=lc), B-frag V^T (col=d)
    bf16x8 ap0 = *(const bf16x8*)&Ps[wid][lc * 72 + lg * 8];
    bf16x8 ap1 = *(const bf16x8*)&Ps[wid][lc * 72 + 32 + lg * 8];
    #pragma unroll
    for (int df = 0; df < 4; ++df) {
      bf16x8 bv0 = *(const bf16x8*)&Vs[(df * 16 + lc) * 72 + lg * 8];
      bf16x8 bv1 = *(const bf16x8*)&Vs[(df * 16 + lc) * 72 + 32 + lg * 8];
      acco[df] = MFMA16(ap0, bv0, acco[df]);
      acco[df] = MFMA16(ap1, bv1, acco[df]);
    }
  }

  // epilogue: fetch lrun for output rows, normalize, write ctx [hi | lo | hi]
  float lr[4];
  #pragma unroll
  for (int r = 0; r < 4; ++r) lr[r] = __shfl(lrun, (lane & 48) | (lg * 4 + r));
  #pragma unroll
  for (int df = 0; df < 4; ++df)
    #pragma unroll
    for (int r = 0; r < 4; ++r) {
      float v = acco[df][r] / lr[r];
      unsigned hi = f2bf(v);
      unsigned lo = f2bf(v - bf2f(hi));
      int rowq = qt * 128 + wid * 16 + lg * 4 + r;
      size_t base = ((size_t)b * 512 + rowq) * 768;
      int c = h * 64 + df * 16 + lc;
      ctxa[base + c]       = (u16)hi;
      ctxa[base + 256 + c] = (u16)lo;
      ctxa[base + 512 + c] = (u16)hi;
    }
}

// ---------------------------------------------------------------------------
extern "C" void kernel_launch(void* const* d_in, const int* in_sizes, int n_in,
                              void* d_out, int out_size, void* d_ws, size_t ws_size,
                              hipStream_t stream) {
  const float* x     = (const float*)d_in[0];
  const int*   adj   = (const int*)d_in[1];
  const float* wqkv  = (const float*)d_in[2];
  const float* wproj = (const float*)d_in[3];
  char* ws = (char*)d_ws;
  u16* xb     = (u16*)(ws + OFF_XB);
  u16* wqkvb  = (u16*)(ws + OFF_WQKV);
  u16* wpa    = (u16*)(ws + OFF_WPA);
  u16* qb     = (u16*)(ws + OFF_QB);
  u16* kb     = (u16*)(ws + OFF_KB);
  u16* vtb    = (u16*)(ws + OFF_VTB);
  u16* ctxa   = (u16*)(ws + OFF_CTXA);
  u64* rowraw = (u64*)(ws + OFF_ROWR);
  u64* colraw = (u64*)(ws + OFF_COLR);
  u64* maskA  = (u64*)(ws + OFF_MASK);
  const size_t MSTRIDE = (size_t)32 * 512 * 8;   // u64 elems per head-mask

  cvt_bf16<<<dim3(2048), 256, 0, stream>>>(x, xb);
  cvt_bf16<<<dim3(96), 256, 0, stream>>>(wqkv, wqkvb);
  cvt_wproj_aug<<<dim3(256), 256, 0, stream>>>(wproj, wpa);
  bitpack_rows<<<dim3(2048), 512, 0, stream>>>(adj, rowraw, maskA);
  transpose_bits<<<dim3(32), 512, 0, stream>>>(rowraw, colraw, maskA + MSTRIDE);
  mask23<<<dim3(32, 8), 64, 0, stream>>>(rowraw, colraw, maskA + 2 * MSTRIDE, maskA + 3 * MSTRIDE);
  gemm_bt<0><<<dim3(128, 6), 256, 0, stream>>>(xb, wqkvb, 256, qb, kb, vtb, nullptr);
  attn<<<dim3(4, 128), 512, 0, stream>>>(qb, kb, vtb, maskA, ctxa);
  gemm_bt<1><<<dim3(128, 2), 256, 0, stream>>>(ctxa, wpa, 768, nullptr, nullptr, nullptr, (float*)d_out);
}